// Round 1
// baseline (472.988 us; speedup 1.0000x reference)
//
#include <hip/hip_runtime.h>
#include <hip/hip_bf16.h>
#include <stdint.h>

#define NROW 8192
#define INF  512
#define OUTF 256

typedef __attribute__((ext_vector_type(8))) short bf16x8;
typedef __attribute__((ext_vector_type(4))) float f32x4;

__device__ __forceinline__ unsigned short f2bf(float x) {
  union { float f; unsigned u; } v; v.f = x;
  unsigned r = v.u + 0x7fffu + ((v.u >> 16) & 1u);   // RNE
  return (unsigned short)(r >> 16);
}

__device__ __forceinline__ void async_cp16(const void* g, void* l) {
  __builtin_amdgcn_global_load_lds((const __attribute__((address_space(1))) void*)g,
                                   (__attribute__((address_space(3))) void*)l,
                                   16, 0, 0);
}

// ---- k1: rowsum -> d = rsqrt(1+sum), and A fp32 -> bf16 copy ----
__global__ __launch_bounds__(256) void k_rowsum_convert(
    const float* __restrict__ A, unsigned short* __restrict__ Ab,
    float* __restrict__ dv) {
  int w = threadIdx.x >> 6, lane = threadIdx.x & 63;
  int row = blockIdx.x * 4 + w;
  const float4* ar = (const float4*)(A + (size_t)row * NROW);
  ushort4* br = (ushort4*)(Ab + (size_t)row * NROW);
  float s = 0.f;
  #pragma unroll 4
  for (int it = 0; it < NROW / 256; ++it) {
    float4 v = ar[it * 64 + lane];
    s += (v.x + v.y) + (v.z + v.w);
    ushort4 b; b.x = f2bf(v.x); b.y = f2bf(v.y); b.z = f2bf(v.z); b.w = f2bf(v.w);
    br[it * 64 + lane] = b;
  }
  #pragma unroll
  for (int off = 32; off > 0; off >>= 1) s += __shfl_down(s, off, 64);
  if (lane == 0) dv[row] = rsqrtf(1.f + s);
}

// ---- k2: X fp32 -> bf16 ----
__global__ __launch_bounds__(256) void k_convert_x(
    const float4* __restrict__ X4, ushort4* __restrict__ Xs4) {
  int q = blockIdx.x * 256 + threadIdx.x;   // 8192*512/4 threads
  float4 v = X4[q];
  ushort4 h; h.x = f2bf(v.x); h.y = f2bf(v.y); h.z = f2bf(v.z); h.w = f2bf(v.w);
  Xs4[q] = h;
}

// ---- k3: W [512][256] fp32 -> WsT [256][512] bf16 ----
__global__ __launch_bounds__(256) void k_convert_w(
    const float* __restrict__ W, unsigned short* __restrict__ WsT) {
  int idx = blockIdx.x * 256 + threadIdx.x;  // 512*256 threads
  int k = idx >> 8, f = idx & 255;
  WsT[(size_t)f * INF + k] = f2bf(W[idx]);
}

// ---- shared MFMA GEMM skeleton (gemm_bt: both operands K-major bf16) ----
// C[m][n] = sum_k Aop[m][k] * Bop[n][k], M=8192, Ntot=256.
// Tile 128x128, BK=64, 256 threads = 4 waves of 64x64 (4x4 16x16x32 MFMAs).
// Staging via global_load_lds width 16 with XOR chunk swizzle (bank-conflict free frag reads).
template<int KTOT, int KSPLIT, bool EPI>
__global__ __launch_bounds__(256, 2) void k_gemm_bt(
    const unsigned short* __restrict__ Aop,
    const unsigned short* __restrict__ Bop,
    float* __restrict__ Pout,            // !EPI: partials [KSPLIT][NROW][OUTF] fp32
    unsigned short* __restrict__ Yout,   // EPI: bf16 out [NROW][OUTF], scaled by dv[row]
    const float* __restrict__ dv) {
  constexpr int KPS = KTOT / KSPLIT;
  constexpr int NITER = KPS / 64;
  __shared__ unsigned short lA[128 * 64];
  __shared__ unsigned short lB[128 * 64];
  const int t = threadIdx.x;
  const int w = t >> 6, lane = t & 63;
  const int m0 = blockIdx.x * 128;
  const int n0 = blockIdx.y * 128;
  const int kz = blockIdx.z * KPS;
  const int rsub = lane >> 3;        // 0..7 row within 8-row group
  const int csub = lane & 7;         // chunk slot 0..7
  const int swz = csub ^ rsub;       // global chunk this lane fetches
  const int lr = lane & 15, lq = lane >> 4, x7 = lane & 7;
  const int mw = (w >> 1) * 64, nw = (w & 1) * 64;

  f32x4 zero = {0.f, 0.f, 0.f, 0.f};
  f32x4 acc[4][4];
  #pragma unroll
  for (int i = 0; i < 4; ++i) {
    #pragma unroll
    for (int j = 0; j < 4; ++j) acc[i][j] = zero;
  }

  const unsigned short* ga0 = Aop + (size_t)(m0 + w * 8 + rsub) * KTOT + kz + swz * 8;
  const unsigned short* gb0 = Bop + (size_t)(n0 + w * 8 + rsub) * KTOT + kz + swz * 8;

  for (int it = 0; it < NITER; ++it) {
    __syncthreads();
    #pragma unroll
    for (int i = 0; i < 4; ++i) {
      async_cp16(ga0 + (size_t)(i * 32) * KTOT + it * 64, &lA[(i * 32 + w * 8) * 64]);
      async_cp16(gb0 + (size_t)(i * 32) * KTOT + it * 64, &lB[(i * 32 + w * 8) * 64]);
    }
    __syncthreads();
    #pragma unroll
    for (int ks = 0; ks < 2; ++ks) {
      bf16x8 af[4], bfv[4];
      #pragma unroll
      for (int mi = 0; mi < 4; ++mi) {
        int r = mw + mi * 16 + lr;
        af[mi] = *(const bf16x8*)&lA[r * 64 + (((ks * 4 + lq) ^ x7) << 3)];
      }
      #pragma unroll
      for (int ni = 0; ni < 4; ++ni) {
        int r = nw + ni * 16 + lr;
        bfv[ni] = *(const bf16x8*)&lB[r * 64 + (((ks * 4 + lq) ^ x7) << 3)];
      }
      #pragma unroll
      for (int mi = 0; mi < 4; ++mi) {
        #pragma unroll
        for (int ni = 0; ni < 4; ++ni) {
          acc[mi][ni] = __builtin_amdgcn_mfma_f32_16x16x32_bf16(
              af[mi], bfv[ni], acc[mi][ni], 0, 0, 0);
        }
      }
    }
  }

  // Epilogue. C/D layout: col = lane&15, row = (lane>>4)*4 + reg  [m89/m91 verified]
  #pragma unroll
  for (int mi = 0; mi < 4; ++mi) {
    #pragma unroll
    for (int ni = 0; ni < 4; ++ni) {
      f32x4 a = acc[mi][ni];
      int gr0 = m0 + mw + mi * 16 + lq * 4;
      int gc  = n0 + nw + ni * 16 + lr;
      if constexpr (EPI) {
        #pragma unroll
        for (int r = 0; r < 4; ++r) {
          int gr = gr0 + r;
          Yout[(size_t)gr * OUTF + gc] = f2bf(dv[gr] * a[r]);
        }
      } else {
        float* P = Pout + (size_t)blockIdx.z * NROW * OUTF;
        #pragma unroll
        for (int r = 0; r < 4; ++r) {
          P[(size_t)(gr0 + r) * OUTF + gc] = a[r];
        }
      }
    }
  }
}

// ---- k5: transpose Y [8192][256] bf16 -> YT [256][8192] bf16 ----
__global__ __launch_bounds__(256) void k_transpose(
    const unsigned short* __restrict__ Y, unsigned short* __restrict__ YT) {
  __shared__ unsigned short T[64][72];
  int i0 = blockIdx.x * 64, f0 = blockIdx.y * 64;
  int t = threadIdx.x;
  int rr = t >> 4, cc = t & 15;
  #pragma unroll
  for (int p = 0; p < 4; ++p) {
    int r = p * 16 + rr;
    ushort4 v = *(const ushort4*)&Y[(size_t)(i0 + r) * OUTF + f0 + cc * 4];
    T[cc * 4 + 0][r] = v.x; T[cc * 4 + 1][r] = v.y;
    T[cc * 4 + 2][r] = v.z; T[cc * 4 + 3][r] = v.w;
  }
  __syncthreads();
  #pragma unroll
  for (int p = 0; p < 4; ++p) {
    int fr = p * 16 + rr;
    ushort4 v;
    v.x = T[fr][cc * 4 + 0]; v.y = T[fr][cc * 4 + 1];
    v.z = T[fr][cc * 4 + 2]; v.w = T[fr][cc * 4 + 3];
    *(ushort4*)&YT[(size_t)(f0 + fr) * NROW + i0 + cc * 4] = v;
  }
}

// ---- k7: out[i][f] = d[i] * sum_ks P[ks][i][f] ----
__global__ __launch_bounds__(256) void k_reduce(
    const float4* __restrict__ P4, const float* __restrict__ dv,
    float4* __restrict__ o4) {
  int q = blockIdx.x * 256 + threadIdx.x;   // NROW*OUTF/4 threads
  const int QT = NROW * OUTF / 4;
  float4 a = P4[q], b = P4[QT + q], c = P4[2 * QT + q], e = P4[3 * QT + q];
  float dd = dv[q >> 6];                     // (q*4)/256
  float4 r;
  r.x = dd * ((a.x + b.x) + (c.x + e.x));
  r.y = dd * ((a.y + b.y) + (c.y + e.y));
  r.z = dd * ((a.z + b.z) + (c.z + e.z));
  r.w = dd * ((a.w + b.w) + (c.w + e.w));
  o4[q] = r;
}

// ---- fallback (ws too small): fp32, slow but correct ----
__global__ __launch_bounds__(256) void k_rowsum_only(
    const float* __restrict__ A, float* __restrict__ dv) {
  int w = threadIdx.x >> 6, lane = threadIdx.x & 63;
  int row = blockIdx.x * 4 + w;
  const float4* ar = (const float4*)(A + (size_t)row * NROW);
  float s = 0.f;
  for (int it = 0; it < NROW / 256; ++it) {
    float4 v = ar[it * 64 + lane];
    s += (v.x + v.y) + (v.z + v.w);
  }
  #pragma unroll
  for (int off = 32; off > 0; off >>= 1) s += __shfl_down(s, off, 64);
  if (lane == 0) dv[row] = rsqrtf(1.f + s);
}

__global__ __launch_bounds__(256) void k_support_naive(
    const float* __restrict__ X, const float* __restrict__ W,
    const float* __restrict__ dv, float* __restrict__ Y) {
  __shared__ float lX[INF];
  int i = blockIdx.x;
  for (int k = threadIdx.x; k < INF; k += 256) lX[k] = X[(size_t)i * INF + k];
  __syncthreads();
  int f = threadIdx.x;
  float s = 0.f;
  for (int k = 0; k < INF; ++k) s += lX[k] * W[(size_t)k * OUTF + f];
  Y[(size_t)i * OUTF + f] = dv[i] * s;
}

__global__ __launch_bounds__(256) void k_main_naive(
    const float* __restrict__ A, const float* __restrict__ Y,
    const float* __restrict__ dv, float* __restrict__ out) {
  __shared__ float lA[256];
  int i = blockIdx.x, f = threadIdx.x;
  float s = 0.f;
  for (int jb = 0; jb < NROW; jb += 256) {
    __syncthreads();
    lA[threadIdx.x] = A[(size_t)i * NROW + jb + threadIdx.x];
    __syncthreads();
    for (int jj = 0; jj < 256; ++jj) s += lA[jj] * Y[(size_t)(jb + jj) * OUTF + f];
  }
  out[(size_t)i * OUTF + f] = dv[i] * s;
}

extern "C" void kernel_launch(void* const* d_in, const int* in_sizes, int n_in,
                              void* d_out, int out_size, void* d_ws, size_t ws_size,
                              hipStream_t stream) {
  const float* A = (const float*)d_in[0];
  const float* X = (const float*)d_in[1];
  const float* W = (const float*)d_in[2];
  float* out = (float*)d_out;

  const size_t SZ_AB  = (size_t)NROW * NROW * 2;       // 128 MiB
  const size_t SZ_YT  = (size_t)OUTF * NROW * 2;       // 4 MiB
  const size_t SZ_XS  = (size_t)NROW * INF * 2;        // 8 MiB
  const size_t SZ_WST = (size_t)OUTF * INF * 2;        // 256 KiB
  const size_t SZ_YB  = (size_t)NROW * OUTF * 2;       // 4 MiB
  const size_t SZ_D   = (size_t)NROW * 4;              // 32 KiB
  const size_t SZ_P   = (size_t)4 * NROW * OUTF * 4;   // 32 MiB
  const size_t NEED = SZ_AB + SZ_YT + SZ_XS + SZ_WST + SZ_YB + SZ_D + SZ_P;

  char* p = (char*)d_ws;
  if (ws_size >= NEED) {
    unsigned short* Ab  = (unsigned short*)p; p += SZ_AB;
    unsigned short* YT  = (unsigned short*)p; p += SZ_YT;
    unsigned short* Xs  = (unsigned short*)p; p += SZ_XS;
    unsigned short* WsT = (unsigned short*)p; p += SZ_WST;
    unsigned short* Yb  = (unsigned short*)p; p += SZ_YB;
    float* dv = (float*)p; p += SZ_D;
    float* P  = (float*)p;

    k_rowsum_convert<<<dim3(2048), dim3(256), 0, stream>>>(A, Ab, dv);
    k_convert_x<<<dim3(4096), dim3(256), 0, stream>>>((const float4*)X, (ushort4*)Xs);
    k_convert_w<<<dim3(512), dim3(256), 0, stream>>>(W, WsT);
    k_gemm_bt<INF, 1, true><<<dim3(64, 2, 1), dim3(256), 0, stream>>>(
        Xs, WsT, nullptr, Yb, dv);
    k_transpose<<<dim3(128, 4), dim3(256), 0, stream>>>(Yb, YT);
    k_gemm_bt<NROW, 4, false><<<dim3(64, 2, 4), dim3(256), 0, stream>>>(
        Ab, YT, P, nullptr, nullptr);
    k_reduce<<<dim3(2048), dim3(256), 0, stream>>>((const float4*)P, dv, (float4*)out);
  } else {
    float* dv = (float*)p; p += SZ_D;
    float* Y  = (float*)p;
    k_rowsum_only<<<dim3(2048), dim3(256), 0, stream>>>(A, dv);
    k_support_naive<<<dim3(8192), dim3(256), 0, stream>>>(X, W, dv, Y);
    k_main_naive<<<dim3(8192), dim3(256), 0, stream>>>(A, Y, dv, out);
  }
}

// Round 2
// 460.597 us; speedup vs baseline: 1.0269x; 1.0269x over previous
//
#include <hip/hip_runtime.h>
#include <hip/hip_bf16.h>
#include <stdint.h>

#define NROW 8192
#define INF  512
#define OUTF 256

typedef __attribute__((ext_vector_type(8))) short bf16x8;
typedef __attribute__((ext_vector_type(4))) float f32x4;

__device__ __forceinline__ unsigned short f2bf(float x) {
  union { float f; unsigned u; } v; v.f = x;
  unsigned r = v.u + 0x7fffu + ((v.u >> 16) & 1u);   // RNE
  return (unsigned short)(r >> 16);
}
__device__ __forceinline__ unsigned short f2bf_fast(float x) {
  union { float f; unsigned u; } v; v.f = x;
  return (unsigned short)((v.u + 0x8000u) >> 16);    // round-half-up, 2 VALU ops
}

__device__ __forceinline__ void async_cp16(const void* g, void* l) {
  __builtin_amdgcn_global_load_lds((const __attribute__((address_space(1))) void*)g,
                                   (__attribute__((address_space(3))) void*)l,
                                   16, 0, 0);
}

// ---- k1: rowsum -> d = rsqrt(1+sum), and A fp32 -> bf16 copy ----
__global__ __launch_bounds__(256) void k_rowsum_convert(
    const float* __restrict__ A, unsigned short* __restrict__ Ab,
    float* __restrict__ dv) {
  int w = threadIdx.x >> 6, lane = threadIdx.x & 63;
  int row = blockIdx.x * 4 + w;
  const float4* ar = (const float4*)(A + (size_t)row * NROW);
  ushort4* br = (ushort4*)(Ab + (size_t)row * NROW);
  float s = 0.f;
  #pragma unroll 4
  for (int it = 0; it < NROW / 256; ++it) {
    float4 v = ar[it * 64 + lane];
    s += (v.x + v.y) + (v.z + v.w);
    ushort4 b;
    b.x = f2bf_fast(v.x); b.y = f2bf_fast(v.y);
    b.z = f2bf_fast(v.z); b.w = f2bf_fast(v.w);
    br[it * 64 + lane] = b;
  }
  #pragma unroll
  for (int off = 32; off > 0; off >>= 1) s += __shfl_down(s, off, 64);
  if (lane == 0) dv[row] = rsqrtf(1.f + s);
}

// ---- k2: X fp32 -> bf16 ----
__global__ __launch_bounds__(256) void k_convert_x(
    const float4* __restrict__ X4, ushort4* __restrict__ Xs4) {
  int q = blockIdx.x * 256 + threadIdx.x;   // 8192*512/4 threads
  float4 v = X4[q];
  ushort4 h; h.x = f2bf(v.x); h.y = f2bf(v.y); h.z = f2bf(v.z); h.w = f2bf(v.w);
  Xs4[q] = h;
}

// ---- k3: W [512][256] fp32 -> WsT [256][512] bf16 ----
__global__ __launch_bounds__(256) void k_convert_w(
    const float* __restrict__ W, unsigned short* __restrict__ WsT) {
  int idx = blockIdx.x * 256 + threadIdx.x;  // 512*256 threads
  int k = idx >> 8, f = idx & 255;
  WsT[(size_t)f * INF + k] = f2bf(W[idx]);
}

// ---- k4: support GEMM producing YT directly ----
// C[f][m] = sum_k WsT[f][k]*Xs[m][k] = (X@W)[m][f]; YT[f][m] = dv[m]*C.
// Tile 128x128 over (features=256, nodes=8192): grid (2, 64). K=512, NITER=8.
__global__ __launch_bounds__(256, 2) void k_support(
    const unsigned short* __restrict__ WsT,
    const unsigned short* __restrict__ Xs,
    const float* __restrict__ dv,
    unsigned short* __restrict__ YT) {
  __shared__ unsigned short lA[128 * 64];
  __shared__ unsigned short lB[128 * 64];
  const int t = threadIdx.x;
  const int w = t >> 6, lane = t & 63;
  const int m0 = blockIdx.x * 128;   // feature tile
  const int n0 = blockIdx.y * 128;   // node tile
  const int rsub = lane >> 3, csub = lane & 7, swz = csub ^ rsub;
  const int lr = lane & 15, lq = lane >> 4, x7 = lane & 7;
  const int mw = (w >> 1) * 64, nw = (w & 1) * 64;

  f32x4 acc[4][4];
  #pragma unroll
  for (int i = 0; i < 4; ++i)
    #pragma unroll
    for (int j = 0; j < 4; ++j) acc[i][j] = f32x4{0.f, 0.f, 0.f, 0.f};

  const unsigned short* ga0 = WsT + (size_t)(m0 + w * 8 + rsub) * INF + swz * 8;
  const unsigned short* gb0 = Xs  + (size_t)(n0 + w * 8 + rsub) * INF + swz * 8;

  for (int it = 0; it < INF / 64; ++it) {
    __syncthreads();
    #pragma unroll
    for (int i = 0; i < 4; ++i) {
      async_cp16(ga0 + (size_t)(i * 32) * INF + it * 64, &lA[(i * 32 + w * 8) * 64]);
      async_cp16(gb0 + (size_t)(i * 32) * INF + it * 64, &lB[(i * 32 + w * 8) * 64]);
    }
    __syncthreads();
    #pragma unroll
    for (int ks = 0; ks < 2; ++ks) {
      bf16x8 af[4], bfv[4];
      #pragma unroll
      for (int mi = 0; mi < 4; ++mi)
        af[mi] = *(const bf16x8*)&lA[(mw + mi * 16 + lr) * 64 + (((ks * 4 + lq) ^ x7) << 3)];
      #pragma unroll
      for (int ni = 0; ni < 4; ++ni)
        bfv[ni] = *(const bf16x8*)&lB[(nw + ni * 16 + lr) * 64 + (((ks * 4 + lq) ^ x7) << 3)];
      #pragma unroll
      for (int mi = 0; mi < 4; ++mi)
        #pragma unroll
        for (int ni = 0; ni < 4; ++ni)
          acc[mi][ni] = __builtin_amdgcn_mfma_f32_16x16x32_bf16(
              af[mi], bfv[ni], acc[mi][ni], 0, 0, 0);
    }
  }
  // C/D layout: col = lane&15, row = (lane>>4)*4 + reg  [m89/m91]
  #pragma unroll
  for (int mi = 0; mi < 4; ++mi) {
    #pragma unroll
    for (int ni = 0; ni < 4; ++ni) {
      f32x4 a = acc[mi][ni];
      int gr0 = m0 + mw + mi * 16 + lq * 4;    // feature
      int gc  = n0 + nw + ni * 16 + lr;        // node
      float dd = dv[gc];
      #pragma unroll
      for (int r = 0; r < 4; ++r)
        YT[(size_t)(gr0 + r) * NROW + gc] = f2bf(dd * a[r]);
    }
  }
}

// ---- k5: main GEMM, tile 128x256 (full N), split-K=8 ----
// P[z][m][f] = sum_{k in z-slice} Ab[m][k]*YT[f][k]
__global__ __launch_bounds__(256, 2) void k_gemm_main(
    const unsigned short* __restrict__ Ab,   // [8192][8192] bf16
    const unsigned short* __restrict__ YT,   // [256][8192] bf16
    float* __restrict__ P) {                 // [8][8192][256] fp32
  __shared__ unsigned short lA[128 * 64];    // 16 KB
  __shared__ unsigned short lB[256 * 64];    // 32 KB
  const int t = threadIdx.x;
  const int w = t >> 6, lane = t & 63;
  const int m0 = blockIdx.x * 128;
  const int kz = blockIdx.y * 1024;
  const int rsub = lane >> 3, csub = lane & 7, swz = csub ^ rsub;
  const int lr = lane & 15, lq = lane >> 4, x7 = lane & 7;
  const int mw = (w & 1) * 64;               // wave m-offset (64 rows)
  const int nw = (w >> 1) * 128;             // wave n-offset (128 cols)

  f32x4 acc[4][8];
  #pragma unroll
  for (int i = 0; i < 4; ++i)
    #pragma unroll
    for (int j = 0; j < 8; ++j) acc[i][j] = f32x4{0.f, 0.f, 0.f, 0.f};

  const unsigned short* ga0 = Ab + (size_t)(m0 + w * 8 + rsub) * NROW + kz + swz * 8;
  const unsigned short* gb0 = YT + (size_t)(w * 8 + rsub) * NROW + kz + swz * 8;

  for (int it = 0; it < 16; ++it) {
    __syncthreads();
    #pragma unroll
    for (int i = 0; i < 4; ++i)
      async_cp16(ga0 + (size_t)(i * 32) * NROW + it * 64, &lA[(i * 32 + w * 8) * 64]);
    #pragma unroll
    for (int i = 0; i < 8; ++i)
      async_cp16(gb0 + (size_t)(i * 32) * NROW + it * 64, &lB[(i * 32 + w * 8) * 64]);
    __syncthreads();
    #pragma unroll
    for (int ks = 0; ks < 2; ++ks) {
      bf16x8 af[4], bfv[8];
      #pragma unroll
      for (int mi = 0; mi < 4; ++mi)
        af[mi] = *(const bf16x8*)&lA[(mw + mi * 16 + lr) * 64 + (((ks * 4 + lq) ^ x7) << 3)];
      #pragma unroll
      for (int ni = 0; ni < 8; ++ni)
        bfv[ni] = *(const bf16x8*)&lB[(nw + ni * 16 + lr) * 64 + (((ks * 4 + lq) ^ x7) << 3)];
      #pragma unroll
      for (int mi = 0; mi < 4; ++mi)
        #pragma unroll
        for (int ni = 0; ni < 8; ++ni)
          acc[mi][ni] = __builtin_amdgcn_mfma_f32_16x16x32_bf16(
              af[mi], bfv[ni], acc[mi][ni], 0, 0, 0);
    }
  }

  float* Pz = P + (size_t)blockIdx.y * NROW * OUTF;
  #pragma unroll
  for (int mi = 0; mi < 4; ++mi) {
    #pragma unroll
    for (int ni = 0; ni < 8; ++ni) {
      f32x4 a = acc[mi][ni];
      int gr0 = m0 + mw + mi * 16 + lq * 4;
      int gc  = nw + ni * 16 + lr;
      #pragma unroll
      for (int r = 0; r < 4; ++r)
        Pz[(size_t)(gr0 + r) * OUTF + gc] = a[r];
    }
  }
}

// ---- k6: out[i][f] = d[i] * sum_z P[z][i][f] ----
__global__ __launch_bounds__(256) void k_reduce8(
    const float4* __restrict__ P4, const float* __restrict__ dv,
    float4* __restrict__ o4) {
  int q = blockIdx.x * 256 + threadIdx.x;   // NROW*OUTF/4 = 524288 threads
  const int QT = NROW * OUTF / 4;
  float4 s = P4[q];
  #pragma unroll
  for (int z = 1; z < 8; ++z) {
    float4 v = P4[(size_t)z * QT + q];
    s.x += v.x; s.y += v.y; s.z += v.z; s.w += v.w;
  }
  float dd = dv[q >> 6];
  s.x *= dd; s.y *= dd; s.z *= dd; s.w *= dd;
  o4[q] = s;
}

// ---- fallback (ws too small): fp32, slow but correct ----
__global__ __launch_bounds__(256) void k_rowsum_only(
    const float* __restrict__ A, float* __restrict__ dv) {
  int w = threadIdx.x >> 6, lane = threadIdx.x & 63;
  int row = blockIdx.x * 4 + w;
  const float4* ar = (const float4*)(A + (size_t)row * NROW);
  float s = 0.f;
  for (int it = 0; it < NROW / 256; ++it) {
    float4 v = ar[it * 64 + lane];
    s += (v.x + v.y) + (v.z + v.w);
  }
  #pragma unroll
  for (int off = 32; off > 0; off >>= 1) s += __shfl_down(s, off, 64);
  if (lane == 0) dv[row] = rsqrtf(1.f + s);
}

__global__ __launch_bounds__(256) void k_support_naive(
    const float* __restrict__ X, const float* __restrict__ W,
    const float* __restrict__ dv, float* __restrict__ Y) {
  __shared__ float lX[INF];
  int i = blockIdx.x;
  for (int k = threadIdx.x; k < INF; k += 256) lX[k] = X[(size_t)i * INF + k];
  __syncthreads();
  int f = threadIdx.x;
  float s = 0.f;
  for (int k = 0; k < INF; ++k) s += lX[k] * W[(size_t)k * OUTF + f];
  Y[(size_t)i * OUTF + f] = dv[i] * s;
}

__global__ __launch_bounds__(256) void k_main_naive(
    const float* __restrict__ A, const float* __restrict__ Y,
    const float* __restrict__ dv, float* __restrict__ out) {
  __shared__ float lA[256];
  int i = blockIdx.x, f = threadIdx.x;
  float s = 0.f;
  for (int jb = 0; jb < NROW; jb += 256) {
    __syncthreads();
    lA[threadIdx.x] = A[(size_t)i * NROW + jb + threadIdx.x];
    __syncthreads();
    for (int jj = 0; jj < 256; ++jj) s += lA[jj] * Y[(size_t)(jb + jj) * OUTF + f];
  }
  out[(size_t)i * OUTF + f] = dv[i] * s;
}

extern "C" void kernel_launch(void* const* d_in, const int* in_sizes, int n_in,
                              void* d_out, int out_size, void* d_ws, size_t ws_size,
                              hipStream_t stream) {
  const float* A = (const float*)d_in[0];
  const float* X = (const float*)d_in[1];
  const float* W = (const float*)d_in[2];
  float* out = (float*)d_out;

  const size_t SZ_AB  = (size_t)NROW * NROW * 2;       // 128 MiB
  const size_t SZ_YT  = (size_t)OUTF * NROW * 2;       // 4 MiB
  const size_t SZ_XS  = (size_t)NROW * INF * 2;        // 8 MiB
  const size_t SZ_WST = (size_t)OUTF * INF * 2;        // 256 KiB
  const size_t SZ_D   = (size_t)NROW * 4;              // 32 KiB
  const size_t SZ_P   = (size_t)8 * NROW * OUTF * 4;   // 64 MiB
  const size_t NEED = SZ_AB + SZ_YT + SZ_XS + SZ_WST + SZ_D + SZ_P;

  char* p = (char*)d_ws;
  if (ws_size >= NEED) {
    unsigned short* Ab  = (unsigned short*)p; p += SZ_AB;
    unsigned short* YT  = (unsigned short*)p; p += SZ_YT;
    unsigned short* Xs  = (unsigned short*)p; p += SZ_XS;
    unsigned short* WsT = (unsigned short*)p; p += SZ_WST;
    float* dv = (float*)p; p += SZ_D;
    float* P  = (float*)p;

    k_rowsum_convert<<<dim3(2048), dim3(256), 0, stream>>>(A, Ab, dv);
    k_convert_x<<<dim3(4096), dim3(256), 0, stream>>>((const float4*)X, (ushort4*)Xs);
    k_convert_w<<<dim3(512), dim3(256), 0, stream>>>(W, WsT);
    k_support<<<dim3(2, 64), dim3(256), 0, stream>>>(WsT, Xs, dv, YT);
    k_gemm_main<<<dim3(64, 8), dim3(256), 0, stream>>>(Ab, YT, P);
    k_reduce8<<<dim3(2048), dim3(256), 0, stream>>>((const float4*)P, dv, (float4*)out);
  } else {
    float* dv = (float*)p; p += SZ_D;
    float* Y  = (float*)p;
    k_rowsum_only<<<dim3(2048), dim3(256), 0, stream>>>(A, dv);
    k_support_naive<<<dim3(8192), dim3(256), 0, stream>>>(X, W, dv, Y);
    k_main_naive<<<dim3(8192), dim3(256), 0, stream>>>(A, Y, dv, out);
  }
}

// Round 3
// 457.403 us; speedup vs baseline: 1.0341x; 1.0070x over previous
//
#include <hip/hip_runtime.h>
#include <hip/hip_bf16.h>
#include <stdint.h>

#define NROW 8192
#define INF  512
#define OUTF 256

typedef __attribute__((ext_vector_type(8))) short bf16x8;
typedef __attribute__((ext_vector_type(4))) float f32x4;

__device__ __forceinline__ unsigned short f2bf(float x) {
  union { float f; unsigned u; } v; v.f = x;
  unsigned r = v.u + 0x7fffu + ((v.u >> 16) & 1u);   // RNE
  return (unsigned short)(r >> 16);
}
__device__ __forceinline__ unsigned short f2bf_fast(float x) {
  union { float f; unsigned u; } v; v.f = x;
  return (unsigned short)((v.u + 0x8000u) >> 16);    // round-half-up
}
__device__ __forceinline__ float bf2f(unsigned short h) {
  union { unsigned u; float f; } v; v.u = ((unsigned)h) << 16;
  return v.f;
}

__device__ __forceinline__ void async_cp16(const void* g, void* l) {
  __builtin_amdgcn_global_load_lds((const __attribute__((address_space(1))) void*)g,
                                   (__attribute__((address_space(3))) void*)l,
                                   16, 0, 0);
}

// ---- k1: rowsum -> d = rsqrt(1+sum), and A fp32 -> bf16 copy ----
// At BW floor: 256 MB read + 128 MB write.
__global__ __launch_bounds__(256) void k_rowsum_convert(
    const float* __restrict__ A, unsigned short* __restrict__ Ab,
    float* __restrict__ dv) {
  int w = threadIdx.x >> 6, lane = threadIdx.x & 63;
  int row = blockIdx.x * 4 + w;
  const float4* ar = (const float4*)(A + (size_t)row * NROW);
  ushort4* br = (ushort4*)(Ab + (size_t)row * NROW);
  float s = 0.f;
  #pragma unroll 4
  for (int it = 0; it < NROW / 256; ++it) {
    float4 v = ar[it * 64 + lane];
    s += (v.x + v.y) + (v.z + v.w);
    ushort4 b;
    b.x = f2bf_fast(v.x); b.y = f2bf_fast(v.y);
    b.z = f2bf_fast(v.z); b.w = f2bf_fast(v.w);
    br[it * 64 + lane] = b;
  }
  #pragma unroll
  for (int off = 32; off > 0; off >>= 1) s += __shfl_down(s, off, 64);
  if (lane == 0) dv[row] = rsqrtf(1.f + s);
}

// ---- k2: W [512][256] fp32 -> WsT [256][512] bf16 (tiny) ----
__global__ __launch_bounds__(256) void k_convert_w(
    const float* __restrict__ W, unsigned short* __restrict__ WsT) {
  int idx = blockIdx.x * 256 + threadIdx.x;  // 512*256 threads
  int k = idx >> 8, f = idx & 255;
  WsT[(size_t)f * INF + k] = f2bf(W[idx]);
}

// ---- k3: support GEMM, X read as fp32 + converted in-kernel ----
// C[f][m] = sum_k WsT[f][k]*X[m][k]; YT[f][m] = dv[m]*C. Tile 128(f) x 128(m).
__global__ __launch_bounds__(256, 2) void k_support_fx(
    const unsigned short* __restrict__ WsT,
    const float* __restrict__ X,
    const float* __restrict__ dv,
    unsigned short* __restrict__ YT) {
  __shared__ unsigned short lA[128 * 64];   // W-tile, cp16-staged (swizzled)
  __shared__ unsigned short lB[128 * 64];   // X-tile, ds_write-staged (same swizzle)
  const int t = threadIdx.x;
  const int w = t >> 6, lane = t & 63;
  const int m0 = blockIdx.x * 128;   // feature tile
  const int n0 = blockIdx.y * 128;   // node tile
  const int rsub = lane >> 3, csub = lane & 7, swz = csub ^ rsub;
  const int lr = lane & 15, lq = lane >> 4, x7 = lane & 7;
  const int mw = (w >> 1) * 64, nw = (w & 1) * 64;

  // X staging map: thread -> row (t>>1), k-half (t&1)
  const int xrow = t >> 1, xhalf = t & 1;
  const float4* xsrc = (const float4*)(X + (size_t)(n0 + xrow) * INF + xhalf * 32);

  f32x4 acc[4][4];
  #pragma unroll
  for (int i = 0; i < 4; ++i)
    #pragma unroll
    for (int j = 0; j < 4; ++j) acc[i][j] = f32x4{0.f, 0.f, 0.f, 0.f};

  const unsigned short* ga0 = WsT + (size_t)(m0 + w * 8 + rsub) * INF + swz * 8;

  for (int it = 0; it < INF / 64; ++it) {
    __syncthreads();
    #pragma unroll
    for (int i = 0; i < 4; ++i)
      async_cp16(ga0 + (size_t)(i * 32) * INF + it * 64, &lA[(i * 32 + w * 8) * 64]);
    // X: load 8 float4 (32 floats), convert, swizzled ds_write ushort4
    #pragma unroll
    for (int u = 0; u < 8; ++u) {
      float4 v = xsrc[it * 16 + u];           // k = it*64 + xhalf*32 + u*4
      ushort4 b;
      b.x = f2bf(v.x); b.y = f2bf(v.y); b.z = f2bf(v.z); b.w = f2bf(v.w);
      int k = xhalf * 32 + u * 4;
      int chunk = k >> 3, klo = k & 7;
      int slot = chunk ^ (xrow & 7);          // LDS[r][s] = G[r][s^(r&7)]
      *(ushort4*)&lB[xrow * 64 + (slot << 3) + klo] = b;
    }
    __syncthreads();
    #pragma unroll
    for (int ks = 0; ks < 2; ++ks) {
      bf16x8 af[4], bfv[4];
      #pragma unroll
      for (int mi = 0; mi < 4; ++mi)
        af[mi] = *(const bf16x8*)&lA[(mw + mi * 16 + lr) * 64 + (((ks * 4 + lq) ^ x7) << 3)];
      #pragma unroll
      for (int ni = 0; ni < 4; ++ni)
        bfv[ni] = *(const bf16x8*)&lB[(nw + ni * 16 + lr) * 64 + (((ks * 4 + lq) ^ x7) << 3)];
      #pragma unroll
      for (int mi = 0; mi < 4; ++mi)
        #pragma unroll
        for (int ni = 0; ni < 4; ++ni)
          acc[mi][ni] = __builtin_amdgcn_mfma_f32_16x16x32_bf16(
              af[mi], bfv[ni], acc[mi][ni], 0, 0, 0);
    }
  }
  // C/D layout: col = lane&15, row = (lane>>4)*4 + reg  [m89/m91]
  #pragma unroll
  for (int mi = 0; mi < 4; ++mi) {
    #pragma unroll
    for (int ni = 0; ni < 4; ++ni) {
      f32x4 a = acc[mi][ni];
      int gr0 = m0 + mw + mi * 16 + lq * 4;    // feature
      int gc  = n0 + nw + ni * 16 + lr;        // node
      float dd = dv[gc];
      #pragma unroll
      for (int r = 0; r < 4; ++r)
        YT[(size_t)(gr0 + r) * NROW + gc] = f2bf(dd * a[r]);
    }
  }
}

// ---- k4: main GEMM, tile 128x256 (full N), split-K=8, bf16 partials ----
// P[z][m][f] = bf16( sum_{k in z-slice} Ab[m][k]*YT[f][k] )
__global__ __launch_bounds__(256, 2) void k_gemm_main(
    const unsigned short* __restrict__ Ab,   // [8192][8192] bf16
    const unsigned short* __restrict__ YT,   // [256][8192] bf16
    unsigned short* __restrict__ P) {        // [8][8192][256] bf16
  __shared__ unsigned short lA[128 * 64];    // 16 KB
  __shared__ unsigned short lB[256 * 64];    // 32 KB
  const int t = threadIdx.x;
  const int w = t >> 6, lane = t & 63;
  const int m0 = blockIdx.x * 128;
  const int kz = blockIdx.y * 1024;
  const int rsub = lane >> 3, csub = lane & 7, swz = csub ^ rsub;
  const int lr = lane & 15, lq = lane >> 4, x7 = lane & 7;
  const int mw = (w & 1) * 64;               // wave m-offset
  const int nw = (w >> 1) * 128;             // wave n-offset

  f32x4 acc[4][8];
  #pragma unroll
  for (int i = 0; i < 4; ++i)
    #pragma unroll
    for (int j = 0; j < 8; ++j) acc[i][j] = f32x4{0.f, 0.f, 0.f, 0.f};

  const unsigned short* ga0 = Ab + (size_t)(m0 + w * 8 + rsub) * NROW + kz + swz * 8;
  const unsigned short* gb0 = YT + (size_t)(w * 8 + rsub) * NROW + kz + swz * 8;

  for (int it = 0; it < 16; ++it) {
    __syncthreads();
    #pragma unroll
    for (int i = 0; i < 4; ++i)
      async_cp16(ga0 + (size_t)(i * 32) * NROW + it * 64, &lA[(i * 32 + w * 8) * 64]);
    #pragma unroll
    for (int i = 0; i < 8; ++i)
      async_cp16(gb0 + (size_t)(i * 32) * NROW + it * 64, &lB[(i * 32 + w * 8) * 64]);
    __syncthreads();
    #pragma unroll
    for (int ks = 0; ks < 2; ++ks) {
      bf16x8 af[4], bfv[8];
      #pragma unroll
      for (int mi = 0; mi < 4; ++mi)
        af[mi] = *(const bf16x8*)&lA[(mw + mi * 16 + lr) * 64 + (((ks * 4 + lq) ^ x7) << 3)];
      #pragma unroll
      for (int ni = 0; ni < 8; ++ni)
        bfv[ni] = *(const bf16x8*)&lB[(nw + ni * 16 + lr) * 64 + (((ks * 4 + lq) ^ x7) << 3)];
      #pragma unroll
      for (int mi = 0; mi < 4; ++mi)
        #pragma unroll
        for (int ni = 0; ni < 8; ++ni)
          acc[mi][ni] = __builtin_amdgcn_mfma_f32_16x16x32_bf16(
              af[mi], bfv[ni], acc[mi][ni], 0, 0, 0);
    }
  }

  unsigned short* Pz = P + (size_t)blockIdx.y * NROW * OUTF;
  #pragma unroll
  for (int mi = 0; mi < 4; ++mi) {
    #pragma unroll
    for (int ni = 0; ni < 8; ++ni) {
      f32x4 a = acc[mi][ni];
      int gr0 = m0 + mw + mi * 16 + lq * 4;
      int gc  = nw + ni * 16 + lr;
      #pragma unroll
      for (int r = 0; r < 4; ++r)
        Pz[(size_t)(gr0 + r) * OUTF + gc] = f2bf_fast(a[r]);
    }
  }
}

// ---- k5: out[i][f] = d[i] * sum_z bf2f(P[z][i][f]) ----
__global__ __launch_bounds__(256) void k_reduce8(
    const ushort4* __restrict__ P4, const float* __restrict__ dv,
    float4* __restrict__ o4) {
  int q = blockIdx.x * 256 + threadIdx.x;   // NROW*OUTF/4 threads
  const int QT = NROW * OUTF / 4;
  float4 s = {0.f, 0.f, 0.f, 0.f};
  #pragma unroll
  for (int z = 0; z < 8; ++z) {
    ushort4 v = P4[(size_t)z * QT + q];
    s.x += bf2f(v.x); s.y += bf2f(v.y); s.z += bf2f(v.z); s.w += bf2f(v.w);
  }
  float dd = dv[q >> 6];
  s.x *= dd; s.y *= dd; s.z *= dd; s.w *= dd;
  o4[q] = s;
}

// ---- fallback (ws too small): fp32, slow but correct ----
__global__ __launch_bounds__(256) void k_rowsum_only(
    const float* __restrict__ A, float* __restrict__ dv) {
  int w = threadIdx.x >> 6, lane = threadIdx.x & 63;
  int row = blockIdx.x * 4 + w;
  const float4* ar = (const float4*)(A + (size_t)row * NROW);
  float s = 0.f;
  for (int it = 0; it < NROW / 256; ++it) {
    float4 v = ar[it * 64 + lane];
    s += (v.x + v.y) + (v.z + v.w);
  }
  #pragma unroll
  for (int off = 32; off > 0; off >>= 1) s += __shfl_down(s, off, 64);
  if (lane == 0) dv[row] = rsqrtf(1.f + s);
}

__global__ __launch_bounds__(256) void k_support_naive(
    const float* __restrict__ X, const float* __restrict__ W,
    const float* __restrict__ dv, float* __restrict__ Y) {
  __shared__ float lX[INF];
  int i = blockIdx.x;
  for (int k = threadIdx.x; k < INF; k += 256) lX[k] = X[(size_t)i * INF + k];
  __syncthreads();
  int f = threadIdx.x;
  float s = 0.f;
  for (int k = 0; k < INF; ++k) s += lX[k] * W[(size_t)k * OUTF + f];
  Y[(size_t)i * OUTF + f] = dv[i] * s;
}

__global__ __launch_bounds__(256) void k_main_naive(
    const float* __restrict__ A, const float* __restrict__ Y,
    const float* __restrict__ dv, float* __restrict__ out) {
  __shared__ float lA[256];
  int i = blockIdx.x, f = threadIdx.x;
  float s = 0.f;
  for (int jb = 0; jb < NROW; jb += 256) {
    __syncthreads();
    lA[threadIdx.x] = A[(size_t)i * NROW + jb + threadIdx.x];
    __syncthreads();
    for (int jj = 0; jj < 256; ++jj) s += lA[jj] * Y[(size_t)(jb + jj) * OUTF + f];
  }
  out[(size_t)i * OUTF + f] = dv[i] * s;
}

extern "C" void kernel_launch(void* const* d_in, const int* in_sizes, int n_in,
                              void* d_out, int out_size, void* d_ws, size_t ws_size,
                              hipStream_t stream) {
  const float* A = (const float*)d_in[0];
  const float* X = (const float*)d_in[1];
  const float* W = (const float*)d_in[2];
  float* out = (float*)d_out;

  const size_t SZ_AB  = (size_t)NROW * NROW * 2;       // 128 MiB
  const size_t SZ_YT  = (size_t)OUTF * NROW * 2;       // 4 MiB
  const size_t SZ_WST = (size_t)OUTF * INF * 2;        // 256 KiB
  const size_t SZ_D   = (size_t)NROW * 4;              // 32 KiB
  const size_t SZ_P   = (size_t)8 * NROW * OUTF * 2;   // 32 MiB (bf16)
  const size_t NEED = SZ_AB + SZ_YT + SZ_WST + SZ_D + SZ_P;

  char* p = (char*)d_ws;
  if (ws_size >= NEED) {
    unsigned short* Ab  = (unsigned short*)p; p += SZ_AB;
    unsigned short* YT  = (unsigned short*)p; p += SZ_YT;
    unsigned short* WsT = (unsigned short*)p; p += SZ_WST;
    float* dv = (float*)p; p += SZ_D;
    unsigned short* P = (unsigned short*)p;

    k_rowsum_convert<<<dim3(2048), dim3(256), 0, stream>>>(A, Ab, dv);
    k_convert_w<<<dim3(512), dim3(256), 0, stream>>>(W, WsT);
    k_support_fx<<<dim3(2, 64), dim3(256), 0, stream>>>(WsT, X, dv, YT);
    k_gemm_main<<<dim3(64, 8), dim3(256), 0, stream>>>(Ab, YT, P);
    k_reduce8<<<dim3(2048), dim3(256), 0, stream>>>((const ushort4*)P, dv, (float4*)out);
  } else {
    float* dv = (float*)p; p += SZ_D;
    float* Y  = (float*)p;
    k_rowsum_only<<<dim3(2048), dim3(256), 0, stream>>>(A, dv);
    k_support_naive<<<dim3(8192), dim3(256), 0, stream>>>(X, W, dv, Y);
    k_main_naive<<<dim3(8192), dim3(256), 0, stream>>>(A, Y, dv, out);
  }
}

// Round 4
// 454.388 us; speedup vs baseline: 1.0409x; 1.0066x over previous
//
#include <hip/hip_runtime.h>
#include <hip/hip_bf16.h>
#include <stdint.h>

#define NROW 8192
#define INF  512
#define OUTF 256

typedef __attribute__((ext_vector_type(8))) short bf16x8;
typedef __attribute__((ext_vector_type(4))) float f32x4;

__device__ __forceinline__ unsigned short f2bf(float x) {
  union { float f; unsigned u; } v; v.f = x;
  unsigned r = v.u + 0x7fffu + ((v.u >> 16) & 1u);   // RNE
  return (unsigned short)(r >> 16);
}
__device__ __forceinline__ unsigned short f2bf_fast(float x) {
  union { float f; unsigned u; } v; v.f = x;
  return (unsigned short)((v.u + 0x8000u) >> 16);    // round-half-up
}
__device__ __forceinline__ float bf2f(unsigned short h) {
  union { unsigned u; float f; } v; v.u = ((unsigned)h) << 16;
  return v.f;
}

__device__ __forceinline__ void async_cp16(const void* g, void* l) {
  __builtin_amdgcn_global_load_lds((const __attribute__((address_space(1))) void*)g,
                                   (__attribute__((address_space(3))) void*)l,
                                   16, 0, 0);
}

// ---- k1: rowsum only (read-only; also warms L3 with A) ----
__global__ __launch_bounds__(256) void k_rowsum(
    const float* __restrict__ A, float* __restrict__ dv) {
  int w = threadIdx.x >> 6, lane = threadIdx.x & 63;
  int row = blockIdx.x * 4 + w;
  const float4* ar = (const float4*)(A + (size_t)row * NROW);
  float s = 0.f;
  #pragma unroll 4
  for (int it = 0; it < NROW / 256; ++it) {
    float4 v = ar[it * 64 + lane];
    s += (v.x + v.y) + (v.z + v.w);
  }
  #pragma unroll
  for (int off = 32; off > 0; off >>= 1) s += __shfl_down(s, off, 64);
  if (lane == 0) dv[row] = rsqrtf(1.f + s);
}

// ---- k2: W [512][256] fp32 -> WsT [256][512] bf16 (tiny) ----
__global__ __launch_bounds__(256) void k_convert_w(
    const float* __restrict__ W, unsigned short* __restrict__ WsT) {
  int idx = blockIdx.x * 256 + threadIdx.x;  // 512*256 threads
  int k = idx >> 8, f = idx & 255;
  WsT[(size_t)f * INF + k] = f2bf(W[idx]);
}

// ---- k3: support GEMM, X read as fp32 + converted in-kernel ----
// C[f][m] = sum_k WsT[f][k]*X[m][k]; YT[f][m] = dv[m]*C. Tile 128(f) x 128(m).
__global__ __launch_bounds__(256, 2) void k_support_fx(
    const unsigned short* __restrict__ WsT,
    const float* __restrict__ X,
    const float* __restrict__ dv,
    unsigned short* __restrict__ YT) {
  __shared__ unsigned short lA[128 * 64];   // W-tile, cp16-staged (swizzled)
  __shared__ unsigned short lB[128 * 64];   // X-tile, ds_write-staged (same swizzle)
  const int t = threadIdx.x;
  const int w = t >> 6, lane = t & 63;
  const int m0 = blockIdx.x * 128;   // feature tile
  const int n0 = blockIdx.y * 128;   // node tile
  const int rsub = lane >> 3, csub = lane & 7, swz = csub ^ rsub;
  const int lr = lane & 15, lq = lane >> 4, x7 = lane & 7;
  const int mw = (w >> 1) * 64, nw = (w & 1) * 64;

  const int xrow = t >> 1, xhalf = t & 1;
  const float4* xsrc = (const float4*)(X + (size_t)(n0 + xrow) * INF + xhalf * 32);

  f32x4 acc[4][4];
  #pragma unroll
  for (int i = 0; i < 4; ++i)
    #pragma unroll
    for (int j = 0; j < 4; ++j) acc[i][j] = f32x4{0.f, 0.f, 0.f, 0.f};

  const unsigned short* ga0 = WsT + (size_t)(m0 + w * 8 + rsub) * INF + swz * 8;

  for (int it = 0; it < INF / 64; ++it) {
    __syncthreads();
    #pragma unroll
    for (int i = 0; i < 4; ++i)
      async_cp16(ga0 + (size_t)(i * 32) * INF + it * 64, &lA[(i * 32 + w * 8) * 64]);
    #pragma unroll
    for (int u = 0; u < 8; ++u) {
      float4 v = xsrc[it * 16 + u];           // k = it*64 + xhalf*32 + u*4
      ushort4 b;
      b.x = f2bf(v.x); b.y = f2bf(v.y); b.z = f2bf(v.z); b.w = f2bf(v.w);
      int k = xhalf * 32 + u * 4;
      int chunk = k >> 3, klo = k & 7;
      int slot = chunk ^ (xrow & 7);          // LDS[r][s] = G[r][s^(r&7)]
      *(ushort4*)&lB[xrow * 64 + (slot << 3) + klo] = b;
    }
    __syncthreads();
    #pragma unroll
    for (int ks = 0; ks < 2; ++ks) {
      bf16x8 af[4], bfv[4];
      #pragma unroll
      for (int mi = 0; mi < 4; ++mi)
        af[mi] = *(const bf16x8*)&lA[(mw + mi * 16 + lr) * 64 + (((ks * 4 + lq) ^ x7) << 3)];
      #pragma unroll
      for (int ni = 0; ni < 4; ++ni)
        bfv[ni] = *(const bf16x8*)&lB[(nw + ni * 16 + lr) * 64 + (((ks * 4 + lq) ^ x7) << 3)];
      #pragma unroll
      for (int mi = 0; mi < 4; ++mi)
        #pragma unroll
        for (int ni = 0; ni < 4; ++ni)
          acc[mi][ni] = __builtin_amdgcn_mfma_f32_16x16x32_bf16(
              af[mi], bfv[ni], acc[mi][ni], 0, 0, 0);
    }
  }
  #pragma unroll
  for (int mi = 0; mi < 4; ++mi) {
    #pragma unroll
    for (int ni = 0; ni < 4; ++ni) {
      f32x4 a = acc[mi][ni];
      int gr0 = m0 + mw + mi * 16 + lq * 4;    // feature
      int gc  = n0 + nw + ni * 16 + lr;        // node
      float dd = dv[gc];
      #pragma unroll
      for (int r = 0; r < 4; ++r)
        YT[(size_t)(gr0 + r) * NROW + gc] = f2bf(dd * a[r]);
    }
  }
}

// ---- k4: main GEMM reading A fp32 directly (L3-warm), convert in-register ----
// P[z][m][f] = bf16( sum_{k in z-slice} A[m][k]*YT[f][k] ), tile 128x256, split-K=8
__global__ __launch_bounds__(256, 2) void k_gemm_main_f32a(
    const float* __restrict__ A,             // [8192][8192] fp32 (L3-resident)
    const unsigned short* __restrict__ YT,   // [256][8192] bf16
    unsigned short* __restrict__ P) {        // [8][8192][256] bf16
  __shared__ unsigned short lA[128 * 64];    // 16 KB
  __shared__ unsigned short lB[256 * 64];    // 32 KB
  const int t = threadIdx.x;
  const int w = t >> 6, lane = t & 63;
  const int m0 = blockIdx.x * 128;
  const int kz = blockIdx.y * 1024;
  const int rsub = lane >> 3, csub = lane & 7, swz = csub ^ rsub;
  const int lr = lane & 15, lq = lane >> 4, x7 = lane & 7;
  const int mw = (w & 1) * 64;               // wave m-offset
  const int nw = (w >> 1) * 128;             // wave n-offset

  // A staging map: thread -> rows {t>>2, 64+(t>>2)}, quarter q = t&3
  const int arow = t >> 2, aq = t & 3;
  const int aklo = (aq & 1) * 4;             // byte-half within chunk

  f32x4 acc[4][8];
  #pragma unroll
  for (int i = 0; i < 4; ++i)
    #pragma unroll
    for (int j = 0; j < 8; ++j) acc[i][j] = f32x4{0.f, 0.f, 0.f, 0.f};

  const unsigned short* gb0 = YT + (size_t)(w * 8 + rsub) * NROW + kz + swz * 8;

  for (int it = 0; it < 16; ++it) {
    __syncthreads();
    #pragma unroll
    for (int i = 0; i < 8; ++i)
      async_cp16(gb0 + (size_t)(i * 32) * NROW + it * 64, &lB[(i * 32 + w * 8) * 64]);
    // A: each thread stages 2 rows x 4 float4 (64-B segments, 4 lanes/row)
    #pragma unroll
    for (int h = 0; h < 2; ++h) {
      int r = arow + h * 64;
      const float4* asrc = (const float4*)(A + (size_t)(m0 + r) * NROW + kz + it * 64);
      #pragma unroll
      for (int j = 0; j < 4; ++j) {
        float4 v = asrc[aq + 4 * j];          // k = (aq+4j)*4
        ushort4 b;
        b.x = f2bf_fast(v.x); b.y = f2bf_fast(v.y);
        b.z = f2bf_fast(v.z); b.w = f2bf_fast(v.w);
        int chunk = (aq + 4 * j) >> 1;
        int slot = chunk ^ (r & 7);
        *(ushort4*)&lA[r * 64 + (slot << 3) + aklo] = b;
      }
    }
    __syncthreads();
    #pragma unroll
    for (int ks = 0; ks < 2; ++ks) {
      bf16x8 af[4], bfv[8];
      #pragma unroll
      for (int mi = 0; mi < 4; ++mi)
        af[mi] = *(const bf16x8*)&lA[(mw + mi * 16 + lr) * 64 + (((ks * 4 + lq) ^ x7) << 3)];
      #pragma unroll
      for (int ni = 0; ni < 8; ++ni)
        bfv[ni] = *(const bf16x8*)&lB[(nw + ni * 16 + lr) * 64 + (((ks * 4 + lq) ^ x7) << 3)];
      #pragma unroll
      for (int mi = 0; mi < 4; ++mi)
        #pragma unroll
        for (int ni = 0; ni < 8; ++ni)
          acc[mi][ni] = __builtin_amdgcn_mfma_f32_16x16x32_bf16(
              af[mi], bfv[ni], acc[mi][ni], 0, 0, 0);
    }
  }

  unsigned short* Pz = P + (size_t)blockIdx.y * NROW * OUTF;
  #pragma unroll
  for (int mi = 0; mi < 4; ++mi) {
    #pragma unroll
    for (int ni = 0; ni < 8; ++ni) {
      f32x4 a = acc[mi][ni];
      int gr0 = m0 + mw + mi * 16 + lq * 4;
      int gc  = nw + ni * 16 + lr;
      #pragma unroll
      for (int r = 0; r < 4; ++r)
        Pz[(size_t)(gr0 + r) * OUTF + gc] = f2bf_fast(a[r]);
    }
  }
}

// ---- k5: out[i][f] = d[i] * sum_z bf2f(P[z][i][f]) ----
__global__ __launch_bounds__(256) void k_reduce8(
    const ushort4* __restrict__ P4, const float* __restrict__ dv,
    float4* __restrict__ o4) {
  int q = blockIdx.x * 256 + threadIdx.x;   // NROW*OUTF/4 threads
  const int QT = NROW * OUTF / 4;
  float4 s = {0.f, 0.f, 0.f, 0.f};
  #pragma unroll
  for (int z = 0; z < 8; ++z) {
    ushort4 v = P4[(size_t)z * QT + q];
    s.x += bf2f(v.x); s.y += bf2f(v.y); s.z += bf2f(v.z); s.w += bf2f(v.w);
  }
  float dd = dv[q >> 6];
  s.x *= dd; s.y *= dd; s.z *= dd; s.w *= dd;
  o4[q] = s;
}

// ---- fallback (ws too small): fp32, slow but correct ----
__global__ __launch_bounds__(256) void k_support_naive(
    const float* __restrict__ X, const float* __restrict__ W,
    const float* __restrict__ dv, float* __restrict__ Y) {
  __shared__ float lX[INF];
  int i = blockIdx.x;
  for (int k = threadIdx.x; k < INF; k += 256) lX[k] = X[(size_t)i * INF + k];
  __syncthreads();
  int f = threadIdx.x;
  float s = 0.f;
  for (int k = 0; k < INF; ++k) s += lX[k] * W[(size_t)k * OUTF + f];
  Y[(size_t)i * OUTF + f] = dv[i] * s;
}

__global__ __launch_bounds__(256) void k_main_naive(
    const float* __restrict__ A, const float* __restrict__ Y,
    const float* __restrict__ dv, float* __restrict__ out) {
  __shared__ float lA[256];
  int i = blockIdx.x, f = threadIdx.x;
  float s = 0.f;
  for (int jb = 0; jb < NROW; jb += 256) {
    __syncthreads();
    lA[threadIdx.x] = A[(size_t)i * NROW + jb + threadIdx.x];
    __syncthreads();
    for (int jj = 0; jj < 256; ++jj) s += lA[jj] * Y[(size_t)(jb + jj) * OUTF + f];
  }
  out[(size_t)i * OUTF + f] = dv[i] * s;
}

extern "C" void kernel_launch(void* const* d_in, const int* in_sizes, int n_in,
                              void* d_out, int out_size, void* d_ws, size_t ws_size,
                              hipStream_t stream) {
  const float* A = (const float*)d_in[0];
  const float* X = (const float*)d_in[1];
  const float* W = (const float*)d_in[2];
  float* out = (float*)d_out;

  const size_t SZ_YT  = (size_t)OUTF * NROW * 2;       // 4 MiB
  const size_t SZ_WST = (size_t)OUTF * INF * 2;        // 256 KiB
  const size_t SZ_D   = (size_t)NROW * 4;              // 32 KiB
  const size_t SZ_P   = (size_t)8 * NROW * OUTF * 2;   // 32 MiB (bf16)
  const size_t NEED = SZ_YT + SZ_WST + SZ_D + SZ_P;

  char* p = (char*)d_ws;
  if (ws_size >= NEED) {
    unsigned short* YT  = (unsigned short*)p; p += SZ_YT;
    unsigned short* WsT = (unsigned short*)p; p += SZ_WST;
    float* dv = (float*)p; p += SZ_D;
    unsigned short* P = (unsigned short*)p;

    k_convert_w<<<dim3(512), dim3(256), 0, stream>>>(W, WsT);
    k_rowsum<<<dim3(2048), dim3(256), 0, stream>>>(A, dv);
    k_support_fx<<<dim3(2, 64), dim3(256), 0, stream>>>(WsT, X, dv, YT);
    k_gemm_main_f32a<<<dim3(64, 8), dim3(256), 0, stream>>>(A, YT, P);
    k_reduce8<<<dim3(2048), dim3(256), 0, stream>>>((const ushort4*)P, dv, (float4*)out);
  } else {
    float* dv = (float*)p; p += SZ_D;
    float* Y  = (float*)p;
    k_rowsum<<<dim3(2048), dim3(256), 0, stream>>>(A, dv);
    k_support_naive<<<dim3(8192), dim3(256), 0, stream>>>(X, W, dv, Y);
    k_main_naive<<<dim3(8192), dim3(256), 0, stream>>>(A, Y, dv, out);
  }
}